// Round 18
// baseline (194.314 us; speedup 1.0000x reference)
//
#include <hip/hip_runtime.h>
#include <hip/hip_bf16.h>

#define SDIM 2048
#define EDIM 1024

typedef __attribute__((ext_vector_type(8))) short bf16x8;
typedef __attribute__((ext_vector_type(4))) short bf16x4;
typedef __attribute__((ext_vector_type(4))) float f32x4;
typedef __attribute__((ext_vector_type(4))) unsigned int u32x4;
typedef __hip_bfloat16 bf16;
typedef unsigned char fp8;

#define MFMA(a, b, c) __builtin_amdgcn_mfma_f32_16x16x32_bf16((a), (b), (c), 0, 0, 0)

#define GLDS16(g, l)                                                      \
  __builtin_amdgcn_global_load_lds(                                       \
      (const __attribute__((address_space(1))) unsigned int*)(g),         \
      (__attribute__((address_space(3))) unsigned int*)(l), 16, 0, 0)

__device__ __forceinline__ bf16x8 ld8(const bf16* p) {
  return *(const bf16x8*)p;
}
__device__ __forceinline__ float fexp2(float x) {
  float r;
  asm("v_exp_f32 %0, %1" : "=v"(r) : "v"(x));
  return r;
}
__device__ __forceinline__ float fsin_rev(float rev) {  // input: revolutions in [0,1)
  float r;
  asm("v_sin_f32 %0, %1" : "=v"(r) : "v"(rev));
  return r;
}
__device__ __forceinline__ float fcos_rev(float rev) {
  float r;
  asm("v_cos_f32 %0, %1" : "=v"(r) : "v"(rev));
  return r;
}
__device__ __forceinline__ fp8 f32_to_fp8(float v) {
  return (fp8)(__builtin_amdgcn_cvt_pk_fp8_f32(v, v, 0, false) & 0xff);
}

// ---- weight transpose + f32->bf16 cast body
__device__ __forceinline__ void wcast_body(const float* __restrict__ w, bf16* __restrict__ wt,
                                           int blk, int R, int C) {
  __shared__ float tile[32][33];
  int cb = C >> 5;
  int br = blk / cb, bc = blk % cb;
  int r0 = br << 5, c0 = bc << 5;
  int tr = threadIdx.x >> 5, tc = threadIdx.x & 31;
#pragma unroll
  for (int i = 0; i < 32; i += 8)
    tile[tr + i][tc] = w[(size_t)(r0 + tr + i) * C + c0 + tc];
  __syncthreads();
#pragma unroll
  for (int i = 0; i < 32; i += 8)
    wt[(size_t)(c0 + tr + i) * R + r0 + tc] = __float2bfloat16(tile[tc][tr + i]);
}

// ---- one prep launch: Wo cast (0-1023), small casts (1024-1087),
// sinusoidal PE via fast v_sin/v_cos (1088-3135), LayerNorm (3136-7231).
__global__ __launch_bounds__(256) void prep_kernel(
    const float* __restrict__ wo, const float* __restrict__ w0, const float* __restrict__ w1,
    const float* __restrict__ w2, const float* __restrict__ w3, bf16* __restrict__ oo,
    bf16* __restrict__ o0, bf16* __restrict__ o1, bf16* __restrict__ o2, bf16* __restrict__ o3,
    bf16* __restrict__ pe, const float* __restrict__ x, const float* __restrict__ g,
    const float* __restrict__ be, bf16* __restrict__ xn) {
  int blk = blockIdx.x;
  if (blk < 1024) {
    wcast_body(wo, oo, blk, 1024, 1024);
  } else if (blk < 1088) {
    int which = (blk - 1024) >> 4;
    const float* w = which == 0 ? w0 : which == 1 ? w1 : which == 2 ? w2 : w3;
    bf16* o = which == 0 ? o0 : which == 1 ? o1 : which == 2 ? o2 : o3;
    wcast_body(w, o, (blk - 1024) & 15, 128, 128);
  } else if (blk < 3136) {
    // PE row s: interleaved sin/cos, revolution-scaled native trig
    int s = blk - 1088;
#pragma unroll
    for (int it = 0; it < 2; ++it) {
      int i = threadIdx.x + it * 256;  // i in [0,512)
      float div = __expf((float)(2 * i) * (-9.210340371976184f / (float)EDIM));
      float a = (float)s * div;
      float rev = a * 0.15915494309189535f;
      rev = rev - floorf(rev);
      pe[(size_t)s * EDIM + 2 * i] = __float2bfloat16(fsin_rev(rev));
      pe[(size_t)s * EDIM + 2 * i + 1] = __float2bfloat16(fcos_rev(rev));
    }
  } else {
    // LayerNorm (biased var, eps=1e-5) -> bf16 [tok][1024]
    int tok = blk - 3136;
    const float4 v = ((const float4*)(x + (size_t)tok * EDIM))[threadIdx.x];
    float s = v.x + v.y + v.z + v.w;
    float s2 = v.x * v.x + v.y * v.y + v.z * v.z + v.w * v.w;
#pragma unroll
    for (int o = 1; o < 64; o <<= 1) { s += __shfl_xor(s, o); s2 += __shfl_xor(s2, o); }
    __shared__ float ls[8];
    if ((threadIdx.x & 63) == 0) { ls[threadIdx.x >> 6] = s; ls[4 + (threadIdx.x >> 6)] = s2; }
    __syncthreads();
    s = ls[0] + ls[1] + ls[2] + ls[3];
    s2 = ls[4] + ls[5] + ls[6] + ls[7];
    float mu = s * (1.0f / EDIM);
    float rstd = rsqrtf(s2 * (1.0f / EDIM) - mu * mu + 1e-5f);
    int c = threadIdx.x * 4;
    const float4 gv = ((const float4*)g)[threadIdx.x];
    const float4 bv = ((const float4*)be)[threadIdx.x];
    bf16* o = xn + (size_t)tok * EDIM + c;
    o[0] = __float2bfloat16((v.x - mu) * rstd * gv.x + bv.x);
    o[1] = __float2bfloat16((v.y - mu) * rstd * gv.y + bv.y);
    o[2] = __float2bfloat16((v.z - mu) * rstd * gv.z + bv.z);
    o[3] = __float2bfloat16((v.w - mu) * rstd * gv.w + bv.w);
  }
}

// ---- projection bodies: (128 x 128) @ W(128x128) via WT[d][k]
// Q prescale folds 1/32 * log2(e) so attention uses raw v_exp_f32 (exp2).
#define QSCALE 0.045084219879837156f
template <int MODE>
__device__ __forceinline__ void proj_body(const bf16* __restrict__ A, const bf16* __restrict__ WT,
                                          const float* __restrict__ bias, const float* __restrict__ ubias,
                                          const float* __restrict__ vbias, bf16* __restrict__ out0,
                                          bf16* __restrict__ out1, int blk, bf16* tl) {
  const int row0 = blk * 128;
  const int lane = threadIdx.x & 63, wid = threadIdx.x >> 6;
  const int wr = (wid >> 1) * 64, wc = (wid & 1) * 64;
  const int lg = lane >> 4, lr = lane & 15;
  f32x4 acc[4][4] = {};
#pragma unroll
  for (int kf = 0; kf < 4; ++kf) {
    const int k0 = kf * 32 + lg * 8;
    bf16x8 a[4], b[4];
#pragma unroll
    for (int m = 0; m < 4; ++m) a[m] = ld8(A + (size_t)(row0 + wr + m * 16 + lr) * 128 + k0);
#pragma unroll
    for (int n = 0; n < 4; ++n) b[n] = ld8(WT + (size_t)(wc + n * 16 + lr) * 128 + k0);
#pragma unroll
    for (int m = 0; m < 4; ++m)
#pragma unroll
      for (int n = 0; n < 4; ++n) acc[m][n] = MFMA(a[m], b[n], acc[m][n]);
  }
  if constexpr (MODE == 2) {
#pragma unroll
    for (int m = 0; m < 4; ++m)
#pragma unroll
      for (int n = 0; n < 4; ++n) {
        int col = wc + n * 16 + lr;
#pragma unroll
        for (int r = 0; r < 4; ++r) {
          int lrow = wr + m * 16 + lg * 4 + r;
          tl[col * 132 + lrow] = __float2bfloat16(acc[m][n][r] + bias[col]);
        }
      }
    __syncthreads();
    int tok0 = row0 >> 3;
    int b = tok0 >> 11, s0 = tok0 & 2047;
#pragma unroll
    for (int i = 0; i < 4; ++i) {
      int pair = threadIdx.x + 256 * i;
      int h = pair >> 7, d = pair & 127;
      bf16 tmp[16];
#pragma unroll
      for (int j = 0; j < 16; ++j) tmp[j] = tl[d * 132 + j * 8 + h];
      size_t o = ((size_t)((b * 8 + h) * 128 + d)) * SDIM + s0;
      *(bf16x8*)(out0 + o) = *(bf16x8*)(&tmp[0]);
      *(bf16x8*)(out0 + o + 8) = *(bf16x8*)(&tmp[8]);
    }
  } else {
#pragma unroll
    for (int m = 0; m < 4; ++m)
#pragma unroll
      for (int n = 0; n < 4; ++n) {
        int col = wc + n * 16 + lr;
#pragma unroll
        for (int r = 0; r < 4; ++r) {
          int row = row0 + wr + m * 16 + lg * 4 + r;
          float val = acc[m][n][r];
          if constexpr (MODE == 0) {
            int h = row & 7, tok = row >> 3;
            int b = tok >> 11, s = tok & 2047;
            size_t o = ((size_t)((b * 8 + h) * SDIM + s)) * 128 + col;
            val += bias[col];
            out0[o] = __float2bfloat16((val + ubias[h * 128 + col]) * QSCALE);
            out1[o] = __float2bfloat16((val + vbias[h * 128 + col]) * QSCALE);
          } else if constexpr (MODE == 1) {
            int h = row & 7, tok = row >> 3;
            int b = tok >> 11, s = tok & 2047;
            out0[((size_t)((b * 8 + h) * SDIM + s)) * 128 + col] = __float2bfloat16(val + bias[col]);
          } else {
            int h = row & 7, s = row >> 3;
            out0[((size_t)(h * SDIM + s)) * 128 + col] = __float2bfloat16(val);
          }
        }
      }
  }
}

// one launch for Q/K/V/P projections: 256+256+256+128 = 896 blocks
__global__ __launch_bounds__(256) void proj_all(const bf16* __restrict__ xn, const bf16* __restrict__ peb,
                                                const bf16* __restrict__ wqt, const bf16* __restrict__ wkt,
                                                const bf16* __restrict__ wvt, const bf16* __restrict__ wpt,
                                                const float* __restrict__ bq, const float* __restrict__ bk,
                                                const float* __restrict__ bv, const float* __restrict__ ub,
                                                const float* __restrict__ vbias, bf16* __restrict__ qub,
                                                bf16* __restrict__ qvb, bf16* __restrict__ kbb,
                                                bf16* __restrict__ vtb, bf16* __restrict__ pb) {
  __shared__ bf16 tl[128 * 132];
  int blk = blockIdx.x;
  if (blk < 256) proj_body<0>(xn, wqt, bq, ub, vbias, qub, qvb, blk, tl);
  else if (blk < 512) proj_body<1>(xn, wkt, bk, nullptr, nullptr, kbb, nullptr, blk - 256, tl);
  else if (blk < 768) proj_body<2>(xn, wvt, bv, nullptr, nullptr, vtb, nullptr, blk - 512, tl);
  else proj_body<3>(peb, wpt, nullptr, nullptr, nullptr, pb, nullptr, blk - 768, tl);
}

// ---- UNSHIFTED pos-score GEMM, FP8 output: 128q x 256j tiles, 8 waves,
// single-phase LDS transpose (33.8 KB), 256 B row bursts, half the traffic.
__global__ __launch_bounds__(512) void ps_kernel(const bf16* __restrict__ qv, const bf16* __restrict__ p,
                                                 fp8* __restrict__ ps) {
  const int bh = blockIdx.x & 15;
  const int t = blockIdx.x >> 4;                 // 0..127
  const int q0 = (t >> 3) * 128, j0 = (t & 7) * 256;
  const int h = bh & 7;
  const bf16* Aq = qv + (size_t)bh * SDIM * 128;
  const bf16* Ph = p + (size_t)h * SDIM * 128;
  const int lane = threadIdx.x & 63, wid = threadIdx.x >> 6;  // wid 0..7
  const int wr = (wid >> 2) * 64, wc = (wid & 3) * 64;
  const int lg = lane >> 4, lr = lane & 15;
  f32x4 acc[4][4] = {};
#pragma unroll
  for (int kf = 0; kf < 4; ++kf) {
    const int k0 = kf * 32 + lg * 8;
    bf16x8 a[4], b[4];
#pragma unroll
    for (int m = 0; m < 4; ++m) a[m] = ld8(Aq + (size_t)(q0 + wr + m * 16 + lr) * 128 + k0);
#pragma unroll
    for (int n = 0; n < 4; ++n) b[n] = ld8(Ph + (size_t)(j0 + wc + n * 16 + lr) * 128 + k0);
#pragma unroll
    for (int m = 0; m < 4; ++m)
#pragma unroll
      for (int n = 0; n < 4; ++n) acc[m][n] = MFMA(a[m], b[n], acc[m][n]);
  }
  __shared__ fp8 tl[128 * 264];   // 256 + 8 pad (bytes)
#pragma unroll
  for (int m = 0; m < 4; ++m)
#pragma unroll
    for (int n = 0; n < 4; ++n) {
      int jl = wc + n * 16 + lr;
#pragma unroll
      for (int r = 0; r < 4; ++r) {
        int ql = wr + m * 16 + lg * 4 + r;
        tl[ql * 264 + jl] = f32_to_fp8(acc[m][n][r]);
      }
    }
  __syncthreads();
  fp8* po = ps + (size_t)bh * SDIM * SDIM + (size_t)q0 * SDIM + j0;
#pragma unroll
  for (int i = 0; i < 4; ++i) {
    int id = threadIdx.x + 512 * i;            // 0..2047
    int row = id >> 4, seg = id & 15;          // 128 rows x 16 segs x 16 B
    u32x4 v = *(const u32x4*)(tl + row * 264 + seg * 16);
    *(u32x4*)(po + (size_t)row * SDIM + seg * 16) = v;
  }
}

// ---- flash attention (r13 structure, PS now FP8): KVBLK=64, 8-wave 128-q
// blocks, grid 256 = CU count (bh&7 = XCD), K+V LDS dbuf via global_load_lds,
// counted-drain barrier (vmcnt(4) drains exactly stage(t+1); the 4 PS-window
// loads stay in flight), 2-tile unroll, setprio around MFMA.
// PS band read: one 4-aligned u64 window per nf covers pad(<=3)+4 fp8 bytes.
#define PSLOAD(KT, W64)                                                   \
  {                                                                       \
    _Pragma("unroll")                                                     \
    for (int nf = 0; nf < 4; ++nf) {                                      \
      const int K0 = (KT) + nf * 16 + lg * 4;                             \
      const bool a_ = (K0 + 3 <= Q);                                      \
      const fp8* wp = a_ ? (pA + K0 - padA) : (pB + K0 - padB);           \
      W64[nf] = *(const unsigned long long*)wp;                           \
    }                                                                     \
  }

#define STAGE(KT, BUF)                                                    \
  {                                                                       \
    _Pragma("unroll")                                                     \
    for (int i = 0; i < 2; ++i) {                                         \
      int rb = wid * 8 + i * 4;                                           \
      int row = rb + krow_l;                                              \
      GLDS16(Kp + (size_t)((KT) + row) * 128 + ((kc16 ^ (row & 7)) << 3), \
             &kl[BUF][rb * 128]);                                         \
    }                                                                     \
    _Pragma("unroll")                                                     \
    for (int i = 0; i < 2; ++i) {                                         \
      int rb = wid * 16 + i * 8;                                          \
      int d = rb + vrow_l;                                                \
      GLDS16(Vp + (size_t)d * SDIM + (KT) + ((vc8 ^ (d & 7)) << 3),       \
             &vl[BUF][rb * 64]);                                          \
    }                                                                     \
  }

#define TILE(KT, BUF, W64, W64N, PREF)                                    \
  {                                                                       \
    if (PREF) { STAGE((KT) + 64, BUF ^ 1); }                              \
    const bf16* klc = &kl[BUF][0];                                        \
    const bf16* vlc = &vl[BUF][0];                                        \
    f32x4 sc[4] = {};                                                     \
    __builtin_amdgcn_s_setprio(1);                                        \
    _Pragma("unroll")                                                     \
    for (int nf = 0; nf < 4; ++nf) {                                      \
      const int krow = nf * 16 + lr;                                      \
      const bf16* kr = klc + krow * 128;                                  \
      const int sw = (krow & 7) << 3;                                     \
      _Pragma("unroll")                                                   \
      for (int kf = 0; kf < 4; ++kf) {                                    \
        bf16x8 kfrag = *(const bf16x8*)(kr + (((kf * 4 + lg) << 3) ^ sw));\
        sc[nf] = MFMA(kfrag, qfr[kf], sc[nf]);                            \
      }                                                                   \
    }                                                                     \
    __builtin_amdgcn_s_setprio(0);                                        \
    unsigned pw[4];                                                       \
    _Pragma("unroll")                                                     \
    for (int nf = 0; nf < 4; ++nf) {                                      \
      const int K0 = (KT) + nf * 16 + lg * 4;                             \
      const bool a_ = (K0 + 3 <= Q);                                      \
      const bool bp = (K0 >= Q + 2);                                      \
      const int sh8 = (a_ ? padA : padB) << 3;                            \
      unsigned w = (unsigned)(W64[nf] >> sh8);                            \
      if (!a_ && !bp) {                                                   \
        unsigned nw = 0;                                                  \
        _Pragma("unroll")                                                 \
        for (int r = 0; r < 4; ++r) {                                     \
          const int K = K0 + r;                                           \
          unsigned byte = (K <= Q) ? (unsigned)pA[K]                      \
                                   : (K == Q + 1 ? 0u : ((w >> (8 * r)) & 0xffu)); \
          nw |= byte << (8 * r);                                          \
        }                                                                 \
        w = nw;                                                           \
      }                                                                   \
      pw[nf] = w;                                                         \
    }                                                                     \
    if (PREF) { PSLOAD((KT) + 64, W64N); }                                \
    _Pragma("unroll")                                                     \
    for (int nf = 0; nf < 4; ++nf) {                                      \
      float e0 = fexp2(sc[nf][0] + __builtin_amdgcn_cvt_f32_fp8((int)pw[nf], 0)); \
      float e1 = fexp2(sc[nf][1] + __builtin_amdgcn_cvt_f32_fp8((int)pw[nf], 1)); \
      float e2 = fexp2(sc[nf][2] + __builtin_amdgcn_cvt_f32_fp8((int)pw[nf], 2)); \
      float e3 = fexp2(sc[nf][3] + __builtin_amdgcn_cvt_f32_fp8((int)pw[nf], 3)); \
      rsum += (e0 + e1) + (e2 + e3);                                      \
      bf16 tmp[4] = {__float2bfloat16(e0), __float2bfloat16(e1),          \
                     __float2bfloat16(e2), __float2bfloat16(e3)};         \
      *(bf16x4*)(plw + lr * 72 + nf * 16 + lg * 4) = *(bf16x4*)tmp;       \
    }                                                                     \
    bf16x8 pa[2];                                                         \
    _Pragma("unroll")                                                     \
    for (int k2 = 0; k2 < 2; ++k2)                                        \
      pa[k2] = *(const bf16x8*)(plw + lr * 72 + k2 * 32 + lg * 8);        \
    __builtin_amdgcn_s_setprio(1);                                        \
    _Pragma("unroll")                                                     \
    for (int nf = 0; nf < 8; ++nf) {                                      \
      const int d = nf * 16 + lr;                                         \
      const bf16* vr = vlc + d * 64;                                      \
      const int swd = (d & 7) << 3;                                       \
      _Pragma("unroll")                                                   \
      for (int k2 = 0; k2 < 2; ++k2) {                                    \
        bf16x8 vb = *(const bf16x8*)(vr + (((k2 * 4 + lg) << 3) ^ swd));  \
        cacc[nf] = MFMA(pa[k2], vb, cacc[nf]);                            \
      }                                                                   \
    }                                                                     \
    __builtin_amdgcn_s_setprio(0);                                        \
    asm volatile("s_waitcnt vmcnt(4)" ::: "memory");                      \
    __builtin_amdgcn_s_barrier();                                         \
  }

__global__ __launch_bounds__(512) void attn_kernel(const bf16* __restrict__ qu, const bf16* __restrict__ kb,
                                                   const bf16* __restrict__ vt, const fp8* __restrict__ ps,
                                                   bf16* __restrict__ ctx) {
  const int bh = blockIdx.x & 15, qblk = blockIdx.x >> 4;
  const int b = bh >> 3, h = bh & 7;
  const int lane = threadIdx.x & 63, wid = threadIdx.x >> 6;  // wid 0..7
  const int lg = lane >> 4, lr = lane & 15;
  const int q0 = qblk * 128 + wid * 16;
  const bf16* Kp = kb + (size_t)bh * SDIM * 128;
  const bf16* Vp = vt + (size_t)bh * 128 * SDIM;

  const fp8* psbh = ps + (size_t)bh * SDIM * SDIM;
  const int Q = q0 + lr;
  const fp8* pA = psbh + (size_t)(Q + 1) * (SDIM - 1);
  const fp8* pB = psbh + (size_t)(Q + 1) * SDIM - Q - 2;
  const int padA = (int)(((unsigned)(Q + 1) * (SDIM - 1)) & 3);
  const int padB = (int)(((unsigned)(Q + 1) * SDIM - Q - 2) & 3);

  __shared__ bf16 kl[2][64 * 128];   // 32 KB dbuf
  __shared__ bf16 vl[2][128 * 64];   // 32 KB dbuf
  __shared__ bf16 pl[8][16 * 72];    // 18 KB per-wave P
  bf16* plw = &pl[wid][0];

  const int krow_l = lane >> 4, kc16 = lane & 15;
  const int vrow_l = lane >> 3, vc8 = lane & 7;

  bf16x8 qfr[4];
#pragma unroll
  for (int kf = 0; kf < 4; ++kf)
    qfr[kf] = ld8(qu + (size_t)bh * SDIM * 128 + (size_t)(q0 + lr) * 128 + kf * 32 + lg * 8);

  f32x4 cacc[8] = {};
  float rsum = 0.f;

  unsigned long long w64A[4], w64B[4];

  // prologue: stage tile 0 (4 GLDS), then PS windows (4 loads);
  // FIFO => vmcnt(4) drains q-frag loads + staging, leaves PS windows.
  STAGE(0, 0);
  PSLOAD(0, w64A);
  asm volatile("s_waitcnt vmcnt(4)" ::: "memory");
  __builtin_amdgcn_s_barrier();

  for (int t2 = 0; t2 < 32; t2 += 2) {
    const int kt = t2 * 64;
    TILE(kt, 0, w64A, w64B, true);
    TILE(kt + 64, 1, w64B, w64A, (t2 + 2 < 32));
  }

  // rsum: lane holds partial for q = q0+lr; sum across the 4 lane-groups
  rsum += __shfl_xor(rsum, 16);
  rsum += __shfl_xor(rsum, 32);
  float inv[4];
#pragma unroll
  for (int r = 0; r < 4; ++r) inv[r] = 1.0f / __shfl(rsum, lg * 4 + r);
#pragma unroll
  for (int nf = 0; nf < 8; ++nf) {
#pragma unroll
    for (int r = 0; r < 4; ++r) {
      int q = q0 + lg * 4 + r;
      int d = nf * 16 + lr;
      ctx[((size_t)(b * SDIM + q) * 8 + h) * 128 + d] = __float2bfloat16(cacc[nf][r] * inv[r]);
    }
  }
}

// ---- output projection: m97-style staged GEMM (r13, unchanged).
__global__ __launch_bounds__(256) void out_gemm(const bf16* __restrict__ A, const bf16* __restrict__ WT,
                                                const float* __restrict__ bo, float* __restrict__ out) {
  const int bm = blockIdx.x >> 3, bn = blockIdx.x & 7;
  const int lane = threadIdx.x & 63, wid = threadIdx.x >> 6;
  const int wr = (wid >> 1) * 64, wc = (wid & 1) * 64;
  const int lg = lane >> 4, lr = lane & 15;
  const int row0 = bm * 128, col0 = bn * 128;

  __shared__ bf16 al[2][128 * 32];   // 8 KB x2
  __shared__ bf16 bl[2][128 * 32];   // 8 KB x2

  const int srow = lane >> 2, sc = lane & 3;  // staging: 16 rows/instr

  auto stg = [&](int step, int buf) {
#pragma unroll
    for (int i = 0; i < 2; ++i) {
      int rb = wid * 32 + i * 16;
      GLDS16(A + (size_t)(row0 + rb + srow) * 1024 + step * 32 + sc * 8, &al[buf][rb * 32]);
    }
#pragma unroll
    for (int i = 0; i < 2; ++i) {
      int rb = wid * 32 + i * 16;
      GLDS16(WT + (size_t)(col0 + rb + srow) * 1024 + step * 32 + sc * 8, &bl[buf][rb * 32]);
    }
  };

  f32x4 acc[4][4] = {};
  stg(0, 0);
  __syncthreads();
  for (int step = 0; step < 32; ++step) {
    const int buf = step & 1;
    if (step < 31) stg(step + 1, buf ^ 1);
    const bf16* ab = &al[buf][0];
    const bf16* bb = &bl[buf][0];
    bf16x8 a[4], b[4];
#pragma unroll
    for (int m = 0; m < 4; ++m) a[m] = *(const bf16x8*)(ab + (wr + m * 16 + lr) * 32 + lg * 8);
#pragma unroll
    for (int n = 0; n < 4; ++n) b[n] = *(const bf16x8*)(bb + (wc + n * 16 + lr) * 32 + lg * 8);
#pragma unroll
    for (int m = 0; m < 4; ++m)
#pragma unroll
      for (int n = 0; n < 4; ++n) acc[m][n] = MFMA(a[m], b[n], acc[m][n]);
    __syncthreads();
  }
#pragma unroll
  for (int m = 0; m < 4; ++m)
#pragma unroll
    for (int n = 0; n < 4; ++n) {
      int col = col0 + wc + n * 16 + lr;
#pragma unroll
      for (int r = 0; r < 4; ++r) {
        int row = row0 + wr + m * 16 + lg * 4 + r;
        out[(size_t)row * 1024 + col] = acc[m][n][r] + bo[col];
      }
    }
}

extern "C" void kernel_launch(void* const* d_in, const int* in_sizes, int n_in,
                              void* d_out, int out_size, void* d_ws, size_t ws_size,
                              hipStream_t stream) {
  (void)in_sizes; (void)n_in; (void)out_size;
  const float* x = (const float*)d_in[0];
  const float* gam = (const float*)d_in[1];
  const float* bet = (const float*)d_in[2];
  const float* Wq = (const float*)d_in[3];
  const float* bq = (const float*)d_in[4];
  const float* Wk = (const float*)d_in[5];
  const float* bk = (const float*)d_in[6];
  const float* Wv = (const float*)d_in[7];
  const float* bv = (const float*)d_in[8];
  const float* Wp = (const float*)d_in[9];
  const float* ub = (const float*)d_in[10];
  const float* vbias = (const float*)d_in[11];
  const float* Wo = (const float*)d_in[12];
  const float* bo = (const float*)d_in[13];
  float* out = (float*)d_out;

  char* w = (char*)d_ws;
  size_t off = 0;
  auto take = [&](size_t n) { void* p = w + off; off += (n + 255) & ~(size_t)255; return p; };
  bf16* xn = (bf16*)take((size_t)4096 * 1024 * 2);
  bf16* peb = (bf16*)take((size_t)2048 * 1024 * 2);
  bf16* wqt = (bf16*)take(128 * 128 * 2);
  bf16* wkt = (bf16*)take(128 * 128 * 2);
  bf16* wvt = (bf16*)take(128 * 128 * 2);
  bf16* wpt = (bf16*)take(128 * 128 * 2);
  bf16* wot = (bf16*)take((size_t)1024 * 1024 * 2);
  bf16* qub = (bf16*)take((size_t)16 * 2048 * 128 * 2);
  bf16* qvb = (bf16*)take((size_t)16 * 2048 * 128 * 2);
  bf16* kbb = (bf16*)take((size_t)16 * 2048 * 128 * 2);
  bf16* vtb = (bf16*)take((size_t)16 * 2048 * 128 * 2);
  bf16* pb = (bf16*)take((size_t)8 * 2048 * 128 * 2);
  bf16* ctx = (bf16*)take((size_t)4096 * 1024 * 2);
  fp8* psb = (fp8*)take((size_t)16 * 2048 * 2048 + 4096);  // fp8 + pad: window over-read
  if (off > ws_size) return;

  prep_kernel<<<7232, 256, 0, stream>>>(Wo, Wq, Wk, Wv, Wp, wot, wqt, wkt, wvt, wpt,
                                        peb, x, gam, bet, xn);
  proj_all<<<896, 256, 0, stream>>>(xn, peb, wqt, wkt, wvt, wpt, bq, bk, bv, ub, vbias,
                                    qub, qvb, kbb, vtb, pb);
  ps_kernel<<<2048, 512, 0, stream>>>(qvb, pb, psb);
  attn_kernel<<<256, 512, 0, stream>>>(qub, kbb, vtb, psb, ctx);
  out_gemm<<<256, 256, 0, stream>>>(ctx, wot, bo, out);
}

// Round 19
// 186.600 us; speedup vs baseline: 1.0413x; 1.0413x over previous
//
#include <hip/hip_runtime.h>
#include <hip/hip_bf16.h>

#define SDIM 2048
#define EDIM 1024

typedef __attribute__((ext_vector_type(8))) short bf16x8;
typedef __attribute__((ext_vector_type(4))) short bf16x4;
typedef __attribute__((ext_vector_type(4))) float f32x4;
typedef __hip_bfloat16 bf16;
typedef unsigned char fp8;

#define MFMA(a, b, c) __builtin_amdgcn_mfma_f32_16x16x32_bf16((a), (b), (c), 0, 0, 0)

#define GLDS16(g, l)                                                      \
  __builtin_amdgcn_global_load_lds(                                       \
      (const __attribute__((address_space(1))) unsigned int*)(g),         \
      (__attribute__((address_space(3))) unsigned int*)(l), 16, 0, 0)

__device__ __forceinline__ bf16x8 ld8(const bf16* p) {
  return *(const bf16x8*)p;
}
__device__ __forceinline__ float b2f(short s) {
  union { float f; unsigned u; } v; v.u = ((unsigned)(unsigned short)s) << 16; return v.f;
}
__device__ __forceinline__ float fexp2(float x) {
  float r;
  asm("v_exp_f32 %0, %1" : "=v"(r) : "v"(x));
  return r;
}
__device__ __forceinline__ float fsin_rev(float rev) {  // input: revolutions in [0,1)
  float r;
  asm("v_sin_f32 %0, %1" : "=v"(r) : "v"(rev));
  return r;
}
__device__ __forceinline__ float fcos_rev(float rev) {
  float r;
  asm("v_cos_f32 %0, %1" : "=v"(r) : "v"(rev));
  return r;
}

// ---- weight transpose + f32->bf16 cast body
__device__ __forceinline__ void wcast_body(const float* __restrict__ w, bf16* __restrict__ wt,
                                           int blk, int R, int C) {
  __shared__ float tile[32][33];
  int cb = C >> 5;
  int br = blk / cb, bc = blk % cb;
  int r0 = br << 5, c0 = bc << 5;
  int tr = threadIdx.x >> 5, tc = threadIdx.x & 31;
#pragma unroll
  for (int i = 0; i < 32; i += 8)
    tile[tr + i][tc] = w[(size_t)(r0 + tr + i) * C + c0 + tc];
  __syncthreads();
#pragma unroll
  for (int i = 0; i < 32; i += 8)
    wt[(size_t)(c0 + tr + i) * R + r0 + tc] = __float2bfloat16(tile[tc][tr + i]);
}

// ---- one prep launch: Wo cast (0-1023), small casts (1024-1087),
// sinusoidal PE via fast v_sin/v_cos (1088-3135), LayerNorm (3136-7231).
__global__ __launch_bounds__(256) void prep_kernel(
    const float* __restrict__ wo, const float* __restrict__ w0, const float* __restrict__ w1,
    const float* __restrict__ w2, const float* __restrict__ w3, bf16* __restrict__ oo,
    bf16* __restrict__ o0, bf16* __restrict__ o1, bf16* __restrict__ o2, bf16* __restrict__ o3,
    bf16* __restrict__ pe, const float* __restrict__ x, const float* __restrict__ g,
    const float* __restrict__ be, bf16* __restrict__ xn) {
  int blk = blockIdx.x;
  if (blk < 1024) {
    wcast_body(wo, oo, blk, 1024, 1024);
  } else if (blk < 1088) {
    int which = (blk - 1024) >> 4;
    const float* w = which == 0 ? w0 : which == 1 ? w1 : which == 2 ? w2 : w3;
    bf16* o = which == 0 ? o0 : which == 1 ? o1 : which == 2 ? o2 : o3;
    wcast_body(w, o, (blk - 1024) & 15, 128, 128);
  } else if (blk < 3136) {
    // PE row s: interleaved sin/cos, revolution-scaled native trig
    int s = blk - 1088;
#pragma unroll
    for (int it = 0; it < 2; ++it) {
      int i = threadIdx.x + it * 256;  // i in [0,512)
      float div = __expf((float)(2 * i) * (-9.210340371976184f / (float)EDIM));
      float a = (float)s * div;
      float rev = a * 0.15915494309189535f;
      rev = rev - floorf(rev);
      pe[(size_t)s * EDIM + 2 * i] = __float2bfloat16(fsin_rev(rev));
      pe[(size_t)s * EDIM + 2 * i + 1] = __float2bfloat16(fcos_rev(rev));
    }
  } else {
    // LayerNorm (biased var, eps=1e-5) -> bf16 [tok][1024]
    int tok = blk - 3136;
    const float4 v = ((const float4*)(x + (size_t)tok * EDIM))[threadIdx.x];
    float s = v.x + v.y + v.z + v.w;
    float s2 = v.x * v.x + v.y * v.y + v.z * v.z + v.w * v.w;
#pragma unroll
    for (int o = 1; o < 64; o <<= 1) { s += __shfl_xor(s, o); s2 += __shfl_xor(s2, o); }
    __shared__ float ls[8];
    if ((threadIdx.x & 63) == 0) { ls[threadIdx.x >> 6] = s; ls[4 + (threadIdx.x >> 6)] = s2; }
    __syncthreads();
    s = ls[0] + ls[1] + ls[2] + ls[3];
    s2 = ls[4] + ls[5] + ls[6] + ls[7];
    float mu = s * (1.0f / EDIM);
    float rstd = rsqrtf(s2 * (1.0f / EDIM) - mu * mu + 1e-5f);
    int c = threadIdx.x * 4;
    const float4 gv = ((const float4*)g)[threadIdx.x];
    const float4 bv = ((const float4*)be)[threadIdx.x];
    bf16* o = xn + (size_t)tok * EDIM + c;
    o[0] = __float2bfloat16((v.x - mu) * rstd * gv.x + bv.x);
    o[1] = __float2bfloat16((v.y - mu) * rstd * gv.y + bv.y);
    o[2] = __float2bfloat16((v.z - mu) * rstd * gv.z + bv.z);
    o[3] = __float2bfloat16((v.w - mu) * rstd * gv.w + bv.w);
  }
}

// ---- projection bodies: (128 x 128) @ W(128x128) via WT[d][k]
// Q prescale folds 1/32 * log2(e) so attention uses raw v_exp_f32 (exp2).
#define QSCALE 0.045084219879837156f
template <int MODE>
__device__ __forceinline__ void proj_body(const bf16* __restrict__ A, const bf16* __restrict__ WT,
                                          const float* __restrict__ bias, const float* __restrict__ ubias,
                                          const float* __restrict__ vbias, bf16* __restrict__ out0,
                                          bf16* __restrict__ out1, int blk, bf16* tl) {
  const int row0 = blk * 128;
  const int lane = threadIdx.x & 63, wid = threadIdx.x >> 6;
  const int wr = (wid >> 1) * 64, wc = (wid & 1) * 64;
  const int lg = lane >> 4, lr = lane & 15;
  f32x4 acc[4][4] = {};
#pragma unroll
  for (int kf = 0; kf < 4; ++kf) {
    const int k0 = kf * 32 + lg * 8;
    bf16x8 a[4], b[4];
#pragma unroll
    for (int m = 0; m < 4; ++m) a[m] = ld8(A + (size_t)(row0 + wr + m * 16 + lr) * 128 + k0);
#pragma unroll
    for (int n = 0; n < 4; ++n) b[n] = ld8(WT + (size_t)(wc + n * 16 + lr) * 128 + k0);
#pragma unroll
    for (int m = 0; m < 4; ++m)
#pragma unroll
      for (int n = 0; n < 4; ++n) acc[m][n] = MFMA(a[m], b[n], acc[m][n]);
  }
  if constexpr (MODE == 2) {
#pragma unroll
    for (int m = 0; m < 4; ++m)
#pragma unroll
      for (int n = 0; n < 4; ++n) {
        int col = wc + n * 16 + lr;
#pragma unroll
        for (int r = 0; r < 4; ++r) {
          int lrow = wr + m * 16 + lg * 4 + r;
          tl[col * 132 + lrow] = __float2bfloat16(acc[m][n][r] + bias[col]);
        }
      }
    __syncthreads();
    int tok0 = row0 >> 3;
    int b = tok0 >> 11, s0 = tok0 & 2047;
#pragma unroll
    for (int i = 0; i < 4; ++i) {
      int pair = threadIdx.x + 256 * i;
      int h = pair >> 7, d = pair & 127;
      bf16 tmp[16];
#pragma unroll
      for (int j = 0; j < 16; ++j) tmp[j] = tl[d * 132 + j * 8 + h];
      size_t o = ((size_t)((b * 8 + h) * 128 + d)) * SDIM + s0;
      *(bf16x8*)(out0 + o) = *(bf16x8*)(&tmp[0]);
      *(bf16x8*)(out0 + o + 8) = *(bf16x8*)(&tmp[8]);
    }
  } else {
#pragma unroll
    for (int m = 0; m < 4; ++m)
#pragma unroll
      for (int n = 0; n < 4; ++n) {
        int col = wc + n * 16 + lr;
#pragma unroll
        for (int r = 0; r < 4; ++r) {
          int row = row0 + wr + m * 16 + lg * 4 + r;
          float val = acc[m][n][r];
          if constexpr (MODE == 0) {
            int h = row & 7, tok = row >> 3;
            int b = tok >> 11, s = tok & 2047;
            size_t o = ((size_t)((b * 8 + h) * SDIM + s)) * 128 + col;
            val += bias[col];
            out0[o] = __float2bfloat16((val + ubias[h * 128 + col]) * QSCALE);
            out1[o] = __float2bfloat16((val + vbias[h * 128 + col]) * QSCALE);
          } else if constexpr (MODE == 1) {
            int h = row & 7, tok = row >> 3;
            int b = tok >> 11, s = tok & 2047;
            out0[((size_t)((b * 8 + h) * SDIM + s)) * 128 + col] = __float2bfloat16(val + bias[col]);
          } else {
            int h = row & 7, s = row >> 3;
            out0[((size_t)(h * SDIM + s)) * 128 + col] = __float2bfloat16(val);
          }
        }
      }
  }
}

// one launch for Q/K/V/P projections: 256+256+256+128 = 896 blocks
__global__ __launch_bounds__(256) void proj_all(const bf16* __restrict__ xn, const bf16* __restrict__ peb,
                                                const bf16* __restrict__ wqt, const bf16* __restrict__ wkt,
                                                const bf16* __restrict__ wvt, const bf16* __restrict__ wpt,
                                                const float* __restrict__ bq, const float* __restrict__ bk,
                                                const float* __restrict__ bv, const float* __restrict__ ub,
                                                const float* __restrict__ vbias, bf16* __restrict__ qub,
                                                bf16* __restrict__ qvb, bf16* __restrict__ kbb,
                                                bf16* __restrict__ vtb, bf16* __restrict__ pb) {
  __shared__ bf16 tl[128 * 132];
  int blk = blockIdx.x;
  if (blk < 256) proj_body<0>(xn, wqt, bq, ub, vbias, qub, qvb, blk, tl);
  else if (blk < 512) proj_body<1>(xn, wkt, bk, nullptr, nullptr, kbb, nullptr, blk - 256, tl);
  else if (blk < 768) proj_body<2>(xn, wvt, bv, nullptr, nullptr, vtb, nullptr, blk - 512, tl);
  else proj_body<3>(peb, wpt, nullptr, nullptr, nullptr, pb, nullptr, blk - 768, tl);
}

// ---- UNSHIFTED pos-score GEMM, FP8 output v2: LDS transpose stays bf16
// (conflict-free 2-way writes, as r13); f32->fp8 conversion happens in the
// coalesced store phase (bf16x8 ds_read -> 4x cvt_pk_fp8 -> 8B global write).
__global__ __launch_bounds__(512) void ps_kernel(const bf16* __restrict__ qv, const bf16* __restrict__ p,
                                                 fp8* __restrict__ ps) {
  const int bh = blockIdx.x & 15;
  const int t = blockIdx.x >> 4;                 // 0..127
  const int q0 = (t >> 3) * 128, j0 = (t & 7) * 256;
  const int h = bh & 7;
  const bf16* Aq = qv + (size_t)bh * SDIM * 128;
  const bf16* Ph = p + (size_t)h * SDIM * 128;
  const int lane = threadIdx.x & 63, wid = threadIdx.x >> 6;  // wid 0..7
  const int wr = (wid >> 2) * 64, wc = (wid & 3) * 64;
  const int lg = lane >> 4, lr = lane & 15;
  f32x4 acc[4][4] = {};
#pragma unroll
  for (int kf = 0; kf < 4; ++kf) {
    const int k0 = kf * 32 + lg * 8;
    bf16x8 a[4], b[4];
#pragma unroll
    for (int m = 0; m < 4; ++m) a[m] = ld8(Aq + (size_t)(q0 + wr + m * 16 + lr) * 128 + k0);
#pragma unroll
    for (int n = 0; n < 4; ++n) b[n] = ld8(Ph + (size_t)(j0 + wc + n * 16 + lr) * 128 + k0);
#pragma unroll
    for (int m = 0; m < 4; ++m)
#pragma unroll
      for (int n = 0; n < 4; ++n) acc[m][n] = MFMA(a[m], b[n], acc[m][n]);
  }
  __shared__ bf16 tl[128 * 264];   // bf16, 256 + 8 pad (r13 layout, 2-way-free)
#pragma unroll
  for (int m = 0; m < 4; ++m)
#pragma unroll
    for (int n = 0; n < 4; ++n) {
      int jl = wc + n * 16 + lr;
#pragma unroll
      for (int r = 0; r < 4; ++r) {
        int ql = wr + m * 16 + lg * 4 + r;
        tl[ql * 264 + jl] = __float2bfloat16(acc[m][n][r]);
      }
    }
  __syncthreads();
  fp8* po = ps + (size_t)bh * SDIM * SDIM + (size_t)q0 * SDIM + j0;
#pragma unroll
  for (int i = 0; i < 8; ++i) {
    int id = threadIdx.x + 512 * i;            // 0..4095
    int row = id >> 5, seg = id & 31;          // 128 rows x 32 segs x 8 elems
    bf16x8 v = *(const bf16x8*)(tl + row * 264 + seg * 8);
    unsigned lo = 0, hi = 0;
    lo = __builtin_amdgcn_cvt_pk_fp8_f32(b2f(v[0]), b2f(v[1]), (int)lo, false);
    lo = __builtin_amdgcn_cvt_pk_fp8_f32(b2f(v[2]), b2f(v[3]), (int)lo, true);
    hi = __builtin_amdgcn_cvt_pk_fp8_f32(b2f(v[4]), b2f(v[5]), (int)hi, false);
    hi = __builtin_amdgcn_cvt_pk_fp8_f32(b2f(v[6]), b2f(v[7]), (int)hi, true);
    unsigned long long w = ((unsigned long long)hi << 32) | (unsigned long long)lo;
    *(unsigned long long*)(po + (size_t)row * SDIM + seg * 8) = w;
  }
}

// ---- flash attention (r18 structure, PS FP8): KVBLK=64, 8-wave 128-q
// blocks, grid 256 = CU count (bh&7 = XCD), K+V LDS dbuf via global_load_lds,
// counted-drain barrier (vmcnt(4) drains exactly stage(t+1); the 4 PS-window
// loads stay in flight), 2-tile unroll, setprio around MFMA.
// PS band read: one 4-aligned u64 window per nf covers pad(<=3)+4 fp8 bytes.
#define PSLOAD(KT, W64)                                                   \
  {                                                                       \
    _Pragma("unroll")                                                     \
    for (int nf = 0; nf < 4; ++nf) {                                      \
      const int K0 = (KT) + nf * 16 + lg * 4;                             \
      const bool a_ = (K0 + 3 <= Q);                                      \
      const fp8* wp = a_ ? (pA + K0 - padA) : (pB + K0 - padB);           \
      W64[nf] = *(const unsigned long long*)wp;                           \
    }                                                                     \
  }

#define STAGE(KT, BUF)                                                    \
  {                                                                       \
    _Pragma("unroll")                                                     \
    for (int i = 0; i < 2; ++i) {                                         \
      int rb = wid * 8 + i * 4;                                           \
      int row = rb + krow_l;                                              \
      GLDS16(Kp + (size_t)((KT) + row) * 128 + ((kc16 ^ (row & 7)) << 3), \
             &kl[BUF][rb * 128]);                                         \
    }                                                                     \
    _Pragma("unroll")                                                     \
    for (int i = 0; i < 2; ++i) {                                         \
      int rb = wid * 16 + i * 8;                                          \
      int d = rb + vrow_l;                                                \
      GLDS16(Vp + (size_t)d * SDIM + (KT) + ((vc8 ^ (d & 7)) << 3),       \
             &vl[BUF][rb * 64]);                                          \
    }                                                                     \
  }

#define TILE(KT, BUF, W64, W64N, PREF)                                    \
  {                                                                       \
    if (PREF) { STAGE((KT) + 64, BUF ^ 1); }                              \
    const bf16* klc = &kl[BUF][0];                                        \
    const bf16* vlc = &vl[BUF][0];                                        \
    f32x4 sc[4] = {};                                                     \
    __builtin_amdgcn_s_setprio(1);                                        \
    _Pragma("unroll")                                                     \
    for (int nf = 0; nf < 4; ++nf) {                                      \
      const int krow = nf * 16 + lr;                                      \
      const bf16* kr = klc + krow * 128;                                  \
      const int sw = (krow & 7) << 3;                                     \
      _Pragma("unroll")                                                   \
      for (int kf = 0; kf < 4; ++kf) {                                    \
        bf16x8 kfrag = *(const bf16x8*)(kr + (((kf * 4 + lg) << 3) ^ sw));\
        sc[nf] = MFMA(kfrag, qfr[kf], sc[nf]);                            \
      }                                                                   \
    }                                                                     \
    __builtin_amdgcn_s_setprio(0);                                        \
    unsigned pw[4];                                                       \
    _Pragma("unroll")                                                     \
    for (int nf = 0; nf < 4; ++nf) {                                      \
      const int K0 = (KT) + nf * 16 + lg * 4;                             \
      const bool a_ = (K0 + 3 <= Q);                                      \
      const bool bp = (K0 >= Q + 2);                                      \
      const int sh8 = (a_ ? padA : padB) << 3;                            \
      unsigned w = (unsigned)(W64[nf] >> sh8);                            \
      if (!a_ && !bp) {                                                   \
        unsigned nw = 0;                                                  \
        _Pragma("unroll")                                                 \
        for (int r = 0; r < 4; ++r) {                                     \
          const int K = K0 + r;                                           \
          unsigned byte = (K <= Q) ? (unsigned)pA[K]                      \
                                   : (K == Q + 1 ? 0u : ((w >> (8 * r)) & 0xffu)); \
          nw |= byte << (8 * r);                                          \
        }                                                                 \
        w = nw;                                                           \
      }                                                                   \
      pw[nf] = w;                                                         \
    }                                                                     \
    if (PREF) { PSLOAD((KT) + 64, W64N); }                                \
    _Pragma("unroll")                                                     \
    for (int nf = 0; nf < 4; ++nf) {                                      \
      float e0 = fexp2(sc[nf][0] + __builtin_amdgcn_cvt_f32_fp8((int)pw[nf], 0)); \
      float e1 = fexp2(sc[nf][1] + __builtin_amdgcn_cvt_f32_fp8((int)pw[nf], 1)); \
      float e2 = fexp2(sc[nf][2] + __builtin_amdgcn_cvt_f32_fp8((int)pw[nf], 2)); \
      float e3 = fexp2(sc[nf][3] + __builtin_amdgcn_cvt_f32_fp8((int)pw[nf], 3)); \
      rsum += (e0 + e1) + (e2 + e3);                                      \
      bf16 tmp[4] = {__float2bfloat16(e0), __float2bfloat16(e1),          \
                     __float2bfloat16(e2), __float2bfloat16(e3)};         \
      *(bf16x4*)(plw + lr * 72 + nf * 16 + lg * 4) = *(bf16x4*)tmp;       \
    }                                                                     \
    bf16x8 pa[2];                                                         \
    _Pragma("unroll")                                                     \
    for (int k2 = 0; k2 < 2; ++k2)                                        \
      pa[k2] = *(const bf16x8*)(plw + lr * 72 + k2 * 32 + lg * 8);        \
    __builtin_amdgcn_s_setprio(1);                                        \
    _Pragma("unroll")                                                     \
    for (int nf = 0; nf < 8; ++nf) {                                      \
      const int d = nf * 16 + lr;                                         \
      const bf16* vr = vlc + d * 64;                                      \
      const int swd = (d & 7) << 3;                                       \
      _Pragma("unroll")                                                   \
      for (int k2 = 0; k2 < 2; ++k2) {                                    \
        bf16x8 vb = *(const bf16x8*)(vr + (((k2 * 4 + lg) << 3) ^ swd));  \
        cacc[nf] = MFMA(pa[k2], vb, cacc[nf]);                            \
      }                                                                   \
    }                                                                     \
    __builtin_amdgcn_s_setprio(0);                                        \
    asm volatile("s_waitcnt vmcnt(4)" ::: "memory");                      \
    __builtin_amdgcn_s_barrier();                                         \
  }

__global__ __launch_bounds__(512) void attn_kernel(const bf16* __restrict__ qu, const bf16* __restrict__ kb,
                                                   const bf16* __restrict__ vt, const fp8* __restrict__ ps,
                                                   bf16* __restrict__ ctx) {
  const int bh = blockIdx.x & 15, qblk = blockIdx.x >> 4;
  const int b = bh >> 3, h = bh & 7;
  const int lane = threadIdx.x & 63, wid = threadIdx.x >> 6;  // wid 0..7
  const int lg = lane >> 4, lr = lane & 15;
  const int q0 = qblk * 128 + wid * 16;
  const bf16* Kp = kb + (size_t)bh * SDIM * 128;
  const bf16* Vp = vt + (size_t)bh * 128 * SDIM;

  const fp8* psbh = ps + (size_t)bh * SDIM * SDIM;
  const int Q = q0 + lr;
  const fp8* pA = psbh + (size_t)(Q + 1) * (SDIM - 1);
  const fp8* pB = psbh + (size_t)(Q + 1) * SDIM - Q - 2;
  const int padA = (int)(((unsigned)(Q + 1) * (SDIM - 1)) & 3);
  const int padB = (int)(((unsigned)(Q + 1) * SDIM - Q - 2) & 3);

  __shared__ bf16 kl[2][64 * 128];   // 32 KB dbuf
  __shared__ bf16 vl[2][128 * 64];   // 32 KB dbuf
  __shared__ bf16 pl[8][16 * 72];    // 18 KB per-wave P
  bf16* plw = &pl[wid][0];

  const int krow_l = lane >> 4, kc16 = lane & 15;
  const int vrow_l = lane >> 3, vc8 = lane & 7;

  bf16x8 qfr[4];
#pragma unroll
  for (int kf = 0; kf < 4; ++kf)
    qfr[kf] = ld8(qu + (size_t)bh * SDIM * 128 + (size_t)(q0 + lr) * 128 + kf * 32 + lg * 8);

  f32x4 cacc[8] = {};
  float rsum = 0.f;

  unsigned long long w64A[4], w64B[4];

  // prologue: stage tile 0 (4 GLDS), then PS windows (4 loads);
  // FIFO => vmcnt(4) drains q-frag loads + staging, leaves PS windows.
  STAGE(0, 0);
  PSLOAD(0, w64A);
  asm volatile("s_waitcnt vmcnt(4)" ::: "memory");
  __builtin_amdgcn_s_barrier();

  for (int t2 = 0; t2 < 32; t2 += 2) {
    const int kt = t2 * 64;
    TILE(kt, 0, w64A, w64B, true);
    TILE(kt + 64, 1, w64B, w64A, (t2 + 2 < 32));
  }

  // rsum: lane holds partial for q = q0+lr; sum across the 4 lane-groups
  rsum += __shfl_xor(rsum, 16);
  rsum += __shfl_xor(rsum, 32);
  float inv[4];
#pragma unroll
  for (int r = 0; r < 4; ++r) inv[r] = 1.0f / __shfl(rsum, lg * 4 + r);
#pragma unroll
  for (int nf = 0; nf < 8; ++nf) {
#pragma unroll
    for (int r = 0; r < 4; ++r) {
      int q = q0 + lg * 4 + r;
      int d = nf * 16 + lr;
      ctx[((size_t)(b * SDIM + q) * 8 + h) * 128 + d] = __float2bfloat16(cacc[nf][r] * inv[r]);
    }
  }
}

// ---- output projection: m97-style staged GEMM (r13, unchanged).
__global__ __launch_bounds__(256) void out_gemm(const bf16* __restrict__ A, const bf16* __restrict__ WT,
                                                const float* __restrict__ bo, float* __restrict__ out) {
  const int bm = blockIdx.x >> 3, bn = blockIdx.x & 7;
  const int lane = threadIdx.x & 63, wid = threadIdx.x >> 6;
  const int wr = (wid >> 1) * 64, wc = (wid & 1) * 64;
  const int lg = lane >> 4, lr = lane & 15;
  const int row0 = bm * 128, col0 = bn * 128;

  __shared__ bf16 al[2][128 * 32];   // 8 KB x2
  __shared__ bf16 bl[2][128 * 32];   // 8 KB x2

  const int srow = lane >> 2, sc = lane & 3;  // staging: 16 rows/instr

  auto stg = [&](int step, int buf) {
#pragma unroll
    for (int i = 0; i < 2; ++i) {
      int rb = wid * 32 + i * 16;
      GLDS16(A + (size_t)(row0 + rb + srow) * 1024 + step * 32 + sc * 8, &al[buf][rb * 32]);
    }
#pragma unroll
    for (int i = 0; i < 2; ++i) {
      int rb = wid * 32 + i * 16;
      GLDS16(WT + (size_t)(col0 + rb + srow) * 1024 + step * 32 + sc * 8, &bl[buf][rb * 32]);
    }
  };

  f32x4 acc[4][4] = {};
  stg(0, 0);
  __syncthreads();
  for (int step = 0; step < 32; ++step) {
    const int buf = step & 1;
    if (step < 31) stg(step + 1, buf ^ 1);
    const bf16* ab = &al[buf][0];
    const bf16* bb = &bl[buf][0];
    bf16x8 a[4], b[4];
#pragma unroll
    for (int m = 0; m < 4; ++m) a[m] = *(const bf16x8*)(ab + (wr + m * 16 + lr) * 32 + lg * 8);
#pragma unroll
    for (int n = 0; n < 4; ++n) b[n] = *(const bf16x8*)(bb + (wc + n * 16 + lr) * 32 + lg * 8);
#pragma unroll
    for (int m = 0; m < 4; ++m)
#pragma unroll
      for (int n = 0; n < 4; ++n) acc[m][n] = MFMA(a[m], b[n], acc[m][n]);
    __syncthreads();
  }
#pragma unroll
  for (int m = 0; m < 4; ++m)
#pragma unroll
    for (int n = 0; n < 4; ++n) {
      int col = col0 + wc + n * 16 + lr;
#pragma unroll
      for (int r = 0; r < 4; ++r) {
        int row = row0 + wr + m * 16 + lg * 4 + r;
        out[(size_t)row * 1024 + col] = acc[m][n][r] + bo[col];
      }
    }
}

extern "C" void kernel_launch(void* const* d_in, const int* in_sizes, int n_in,
                              void* d_out, int out_size, void* d_ws, size_t ws_size,
                              hipStream_t stream) {
  (void)in_sizes; (void)n_in; (void)out_size;
  const float* x = (const float*)d_in[0];
  const float* gam = (const float*)d_in[1];
  const float* bet = (const float*)d_in[2];
  const float* Wq = (const float*)d_in[3];
  const float* bq = (const float*)d_in[4];
  const float* Wk = (const float*)d_in[5];
  const float* bk = (const float*)d_in[6];
  const float* Wv = (const float*)d_in[7];
  const float* bv = (const float*)d_in[8];
  const float* Wp = (const float*)d_in[9];
  const float* ub = (const float*)d_in[10];
  const float* vbias = (const float*)d_in[11];
  const float* Wo = (const float*)d_in[12];
  const float* bo = (const float*)d_in[13];
  float* out = (float*)d_out;

  char* w = (char*)d_ws;
  size_t off = 0;
  auto take = [&](size_t n) { void* p = w + off; off += (n + 255) & ~(size_t)255; return p; };
  bf16* xn = (bf16*)take((size_t)4096 * 1024 * 2);
  bf16* peb = (bf16*)take((size_t)2048 * 1024 * 2);
  bf16* wqt = (bf16*)take(128 * 128 * 2);
  bf16* wkt = (bf16*)take(128 * 128 * 2);
  bf16* wvt = (bf16*)take(128 * 128 * 2);
  bf16* wpt = (bf16*)take(128 * 128 * 2);
  bf16* wot = (bf16*)take((size_t)1024 * 1024 * 2);
  bf16* qub = (bf16*)take((size_t)16 * 2048 * 128 * 2);
  bf16* qvb = (bf16*)take((size_t)16 * 2048 * 128 * 2);
  bf16* kbb = (bf16*)take((size_t)16 * 2048 * 128 * 2);
  bf16* vtb = (bf16*)take((size_t)16 * 2048 * 128 * 2);
  bf16* pb = (bf16*)take((size_t)8 * 2048 * 128 * 2);
  bf16* ctx = (bf16*)take((size_t)4096 * 1024 * 2);
  fp8* psb = (fp8*)take((size_t)16 * 2048 * 2048 + 4096);  // fp8 + pad: window over-read
  if (off > ws_size) return;

  prep_kernel<<<7232, 256, 0, stream>>>(Wo, Wq, Wk, Wv, Wp, wot, wqt, wkt, wvt, wpt,
                                        peb, x, gam, bet, xn);
  proj_all<<<896, 256, 0, stream>>>(xn, peb, wqt, wkt, wvt, wpt, bq, bk, bv, ub, vbias,
                                    qub, qvb, kbb, vtb, pb);
  ps_kernel<<<2048, 512, 0, stream>>>(qvb, pb, psb);
  attn_kernel<<<256, 512, 0, stream>>>(qub, kbb, vtb, psb, ctx);
  out_gemm<<<256, 256, 0, stream>>>(ctx, wot, bo, out);
}